// Round 10
// baseline (306.267 us; speedup 1.0000x reference)
//
#include <hip/hip_runtime.h>

typedef unsigned short u16;
typedef unsigned int   u32;
typedef __attribute__((ext_vector_type(8))) short bf16x8;
typedef __attribute__((ext_vector_type(4))) float f32x4;

#define SCALE 0.17677669529663687f  // 32^-0.5

__device__ __forceinline__ u16 f2bf(float f){
  u32 x = __float_as_uint(f);
  x += 0x7fffu + ((x >> 16) & 1u);   // RNE
  return (u16)(x >> 16);
}
__device__ __forceinline__ float bf2f(u16 u){
  return __uint_as_float(((u32)u) << 16);
}

// ---- ws layout (bytes) ----
// 0        : qkvw_bf16   [1536][512]            1,572,864
// 1572864  : Wp bf16 (proj W, frag-permuted)      524,288
// 2097152  : biasT bf16  [16][64][16][4] permuted 131,072
// 2228224  : scaleT bf16 (same layout)            131,072
// 2359296  : qkv_s bf16 [1024][16][3][64][32]   201,326,592
// 203685888: x_bf16 [65536][512]                 67,108,864

// ---------------- prep: weights->bf16 (proj W permuted), expand rel tables ----------------
// Wp layout: index j -> e=j&7, lg=(j>>3)&3, lq=(j>>5)&15, ch=(j>>9)&15, ct=j>>13
//   Wp[j] = projw[(ct*16+lq)*512 + ch*32 + lg*8 + e]
// so a proj B-frag (64 lanes, lane=(lg<<4)|lq) for (ct,ch) is one contiguous 2KB load.
// bias/scale tables permuted: [h][row][lq][j] (j = col>>4, lq = col&15)
__global__ void prep_kernel(const float* __restrict__ qkvw, const float* __restrict__ projw,
                            const float* __restrict__ table, const int* __restrict__ relidx,
                            u16* __restrict__ qkvw_b, u16* __restrict__ Wp,
                            u16* __restrict__ biasT, u16* __restrict__ scaleT){
  int i = blockIdx.x * 256 + threadIdx.x;
  if (i < 786432) {
    qkvw_b[i] = f2bf(qkvw[i]);
  } else if (i < 1048576) {
    int j = i - 786432;
    const int e  = j & 7, lg = (j >> 3) & 3, lq = (j >> 5) & 15;
    const int ch = (j >> 9) & 15, ct = j >> 13;
    Wp[j] = f2bf(projw[(ct*16 + lq)*512 + ch*32 + lg*8 + e]);
  } else if (i < 1114112) {
    int j = i - 1048576; int h = j >> 12, rc = j & 4095;
    int idx = relidx[rc];
    int row = rc >> 6, col = rc & 63;
    int noff = h*4096 + row*64 + (col & 15)*4 + (col >> 4);
    biasT [noff] = f2bf(table[idx*32 + h]);
    scaleT[noff] = f2bf(table[idx*32 + 16 + h]);
  }
}

// ---------------- x (fp32) -> bf16 ----------------
__global__ void xconv_kernel(const float* __restrict__ x, u16* __restrict__ xb){
  size_t i = (size_t)blockIdx.x * 256 + threadIdx.x;
  const float4* xp = (const float4*)x;
  float4 a = xp[2*i], b = xp[2*i+1];
  union { u16 u[8]; uint4 v; } o;
  o.u[0]=f2bf(a.x); o.u[1]=f2bf(a.y); o.u[2]=f2bf(a.z); o.u[3]=f2bf(a.w);
  o.u[4]=f2bf(b.x); o.u[5]=f2bf(b.y); o.u[6]=f2bf(b.z); o.u[7]=f2bf(b.w);
  *(uint4*)(xb + 8*i) = o.v;
}

// ============ qkv GEMM (r4 main loop) + scatter epilogue to [bh][3][64][32] ============
__global__ __launch_bounds__(512, 2) void gemm_qkv_kernel(
    const u16* __restrict__ A, const u16* __restrict__ W,
    const float* __restrict__ bias, u16* __restrict__ outp)
{
  __shared__ u16 lds[3][16384];   // 3 x 32KB = 96KB
  const int tid = threadIdx.x, lane = tid & 63, wid = tid >> 6;
  const int wave_base = tid & ~63;

  const int cpx = gridDim.x >> 3;   // bijective XCD swizzle (1536 % 8 == 0)
  const int bid = (blockIdx.x & 7) * cpx + (blockIdx.x >> 3);
  const int mt = bid / 6, nt = bid % 6;
  const size_t m0 = (size_t)mt * 256;
  const int n0 = nt * 256;
  const int wm = wid >> 2, wn = wid & 3;

  const f32x4 z = {0.f, 0.f, 0.f, 0.f};
  f32x4 acc[8][4];
#pragma unroll
  for (int i = 0; i < 8; i++)
#pragma unroll
    for (int j = 0; j < 4; j++) acc[i][j] = z;

  auto stageA = [&](int ch){
    const int slot = ch % 3;
    const int kb = ch * 32;
#pragma unroll
    for (int c = 0; c < 2; ++c){
      const int t = c*512 + tid;
      const int row = t >> 2, sl = t & 3;
      const int lsl = sl ^ ((row >> 1) & 3);
      const u16* ga = A + (m0 + row)*512 + kb + lsl*8;
      u16* la = &lds[slot][(size_t)(c*512 + wave_base)*8];
      __builtin_amdgcn_global_load_lds((const __attribute__((address_space(1))) u32*)ga,
                                       (__attribute__((address_space(3))) u32*)la, 16, 0, 0);
    }
  };
  auto stageB = [&](int ch){
    const int slot = ch % 3;
    const int kb = ch * 32;
#pragma unroll
    for (int c = 0; c < 2; ++c){
      const int t = c*512 + tid;
      const int col = t >> 2, sl = t & 3;
      const int lsl = sl ^ ((col >> 1) & 3);
      const u16* gb = W + (size_t)(n0 + col)*512 + kb + lsl*8;
      u16* lb = &lds[slot][8192 + (size_t)(c*512 + wave_base)*8];
      __builtin_amdgcn_global_load_lds((const __attribute__((address_space(1))) u32*)gb,
                                       (__attribute__((address_space(3))) u32*)lb, 16, 0, 0);
    }
  };

  stageA(0); stageB(0);
  stageA(1); stageB(1);
  asm volatile("s_waitcnt vmcnt(4)" ::: "memory");
  __builtin_amdgcn_s_barrier();

  const int lq = lane & 15, lk = lane >> 4;
#pragma unroll
  for (int ch = 0; ch < 16; ++ch){
    const int slot = ch % 3;
    const u16* As = &lds[slot][0];
    const u16* Bs = &lds[slot][8192];
    bf16x8 af[4], bfr[4], af2[4];

#pragma unroll
    for (int i = 0; i < 4; ++i){
      const int row = wm*128 + i*16 + lq;
      af[i]  = *(const bf16x8*)&As[row*32 + (lk ^ ((row >> 1) & 3))*8];
      const int col = wn*64 + i*16 + lq;
      bfr[i] = *(const bf16x8*)&Bs[col*32 + (lk ^ ((col >> 1) & 3))*8];
    }
    if (ch + 2 < 16) stageA(ch + 2);
    __builtin_amdgcn_s_barrier();
    asm volatile("s_waitcnt lgkmcnt(0)" ::: "memory");
    __builtin_amdgcn_sched_barrier(0);
    __builtin_amdgcn_s_setprio(1);
#pragma unroll
    for (int i = 0; i < 4; ++i)
#pragma unroll
      for (int j = 0; j < 4; ++j)
        acc[i][j] = __builtin_amdgcn_mfma_f32_16x16x32_bf16(af[i], bfr[j], acc[i][j], 0, 0, 0);
    __builtin_amdgcn_s_setprio(0);
    __builtin_amdgcn_s_barrier();

#pragma unroll
    for (int i = 0; i < 4; ++i){
      const int row = wm*128 + 64 + i*16 + lq;
      af2[i] = *(const bf16x8*)&As[row*32 + (lk ^ ((row >> 1) & 3))*8];
    }
    if (ch + 2 < 16) stageB(ch + 2);
    __builtin_amdgcn_s_barrier();
    asm volatile("s_waitcnt lgkmcnt(0)" ::: "memory");
    __builtin_amdgcn_sched_barrier(0);
    __builtin_amdgcn_s_setprio(1);
#pragma unroll
    for (int i = 0; i < 4; ++i)
#pragma unroll
      for (int j = 0; j < 4; ++j)
        acc[4+i][j] = __builtin_amdgcn_mfma_f32_16x16x32_bf16(af2[i], bfr[j], acc[4+i][j], 0, 0, 0);
    __builtin_amdgcn_s_setprio(0);
    if (ch < 14)       { asm volatile("s_waitcnt vmcnt(4)" ::: "memory"); }
    else if (ch == 14) { asm volatile("s_waitcnt vmcnt(0)" ::: "memory"); }
    if (ch < 15) __builtin_amdgcn_s_barrier();
  }

  // scatter epilogue -> qkv_s[b][h][which][n][32]; q pre-scaled.
  const int lr = (lane >> 4) << 2;
  const int lc = lane & 15;
  u16* o = outp;
  float bv[4], sc[4]; int pb[4];
#pragma unroll
  for (int nf = 0; nf < 4; ++nf){
    const int col = n0 + wn*64 + nf*16 + lc;
    bv[nf] = bias[col];
    sc[nf] = (col < 512) ? SCALE : 1.f;
    const int which = col >> 9, h = (col >> 5) & 15, d = col & 31;
    pb[nf] = (h*3 + which)*2048 + d;
  }
#pragma unroll
  for (int mf = 0; mf < 8; ++mf){
#pragma unroll
    for (int r = 0; r < 4; ++r){
      const int row = (int)m0 + wm*128 + mf*16 + lr + r;
      const size_t base = (size_t)(row >> 6) * 98304 + (row & 63)*32;
#pragma unroll
      for (int nf = 0; nf < 4; ++nf)
        o[base + pb[nf]] = f2bf((acc[mf][nf][r] + bv[nf]) * sc[nf]);
    }
  }
}

// ============ FUSED attention + proj: one block per window b ============
// 8 waves. Attn phase (r9-validated body): wave w owns heads 2w,2w+1;
// coalesced per-head loads from qkv_s; V per-wave LDS with (row>>3)&3 slot
// XOR; in-reg softmax (permuted ushort4 tables); O -> swizzled LDS tile
// (r8-validated: 16B-slot s of row r at phys s^(r&7)).
// One __syncthreads. Proj phase (r8 A-path + permuted-W B-path): wave w
// computes cols [w*64,+64); A-frags from O tile; B-frags = single 2KB
// coalesced loads from Wp (L2-resident); 16 chunks, no barriers.
__global__ __launch_bounds__(512) void attnproj_kernel(
    const u16* __restrict__ qkv, const u16* __restrict__ biasT,
    const u16* __restrict__ scaleT, const u16* __restrict__ Wp,
    const float* __restrict__ projb, float* __restrict__ out)
{
  __shared__ u16 O[32768];          // 64KB swizzled O tile [64][512]
  __shared__ u16 scratch[8][3200];  // per wave: vs[64][32] + Ps[16][72]
  const int tid = threadIdx.x, lane = tid & 63, wid = tid >> 6;
  const int lq = lane & 15, lg = lane >> 4;
  const int b = blockIdx.x;
  u16* vs = &scratch[wid][0];
  u16* Ps = &scratch[wid][2048];
  const f32x4 z = {0.f, 0.f, 0.f, 0.f};

#pragma unroll
  for (int hh = 0; hh < 2; ++hh){
    const int h = wid*2 + hh;
    const u16* qb = qkv + ((size_t)b*16 + h) * 6144;
    asm volatile("s_waitcnt lgkmcnt(0)" ::: "memory");   // prev head's vs reads done
    __builtin_amdgcn_sched_barrier(0);
    // stage V[64][32] -> vs with slot XOR (coalesced 1KB loads)
#pragma unroll
    for (int c = 0; c < 4; ++c){
      const int u = c*64 + lane, row = u >> 2, sl = u & 3;
      uint4 t = *(const uint4*)(qb + 4096 + row*32 + sl*8);
      *(uint4*)&vs[row*32 + (sl ^ ((row >> 3) & 3))*8] = t;
    }
    // K frags direct global->reg (coalesced)
    bf16x8 kf[4];
#pragma unroll
    for (int i = 0; i < 4; ++i)
      kf[i] = *(const bf16x8*)(qb + 2048 + (i*16 + lq)*32 + lg*8);

    f32x4 o[4][2];
#pragma unroll
    for (int i = 0; i < 4; ++i){ o[i][0] = z; o[i][1] = z; }

    const u16* bT = biasT + h*4096;
    const u16* sT = scaleT + h*4096;

    asm volatile("s_waitcnt lgkmcnt(0)" ::: "memory");   // vs staged
    __builtin_amdgcn_sched_barrier(0);

#pragma unroll
    for (int i = 0; i < 4; ++i){
      bf16x8 qf = *(const bf16x8*)(qb + (i*16 + lq)*32 + lg*8);
      f32x4 s[4];
#pragma unroll
      for (int j = 0; j < 4; ++j)
        s[j] = __builtin_amdgcn_mfma_f32_16x16x32_bf16(qf, kf[j], z, 0, 0, 0);

#pragma unroll
      for (int r = 0; r < 4; ++r){
        const int row = i*16 + lg*4 + r;
        const ushort4 b4 = *(const ushort4*)&bT[row*64 + lq*4];
        const ushort4 s4 = *(const ushort4*)&sT[row*64 + lq*4];
        float vals[4];
        vals[0] = s[0][r] + bf2f(b4.x);
        vals[1] = s[1][r] + bf2f(b4.y);
        vals[2] = s[2][r] + bf2f(b4.z);
        vals[3] = s[3][r] + bf2f(b4.w);
        float mx = fmaxf(fmaxf(vals[0], vals[1]), fmaxf(vals[2], vals[3]));
        mx = fmaxf(mx, __shfl_xor(mx, 1));
        mx = fmaxf(mx, __shfl_xor(mx, 2));
        mx = fmaxf(mx, __shfl_xor(mx, 4));
        mx = fmaxf(mx, __shfl_xor(mx, 8));
        float sm = 0.f;
#pragma unroll
        for (int j = 0; j < 4; ++j){ vals[j] = __expf(vals[j] - mx); sm += vals[j]; }
        sm += __shfl_xor(sm, 1);
        sm += __shfl_xor(sm, 2);
        sm += __shfl_xor(sm, 4);
        sm += __shfl_xor(sm, 8);
        const float inv = 1.f / sm;
        const u16 sv[4] = {s4.x, s4.y, s4.z, s4.w};
#pragma unroll
        for (int j = 0; j < 4; ++j)
          Ps[(lg*4 + r)*72 + j*16 + lq] = f2bf(vals[j] * inv * bf2f(sv[j]));
      }
      asm volatile("s_waitcnt lgkmcnt(0)" ::: "memory");   // Ps written
      __builtin_amdgcn_sched_barrier(0);
#pragma unroll
      for (int kc = 0; kc < 2; ++kc){
        bf16x8 pa = *(const bf16x8*)&Ps[lq*72 + kc*32 + lg*8];
#pragma unroll
        for (int c2 = 0; c2 < 2; ++c2){
          union { u16 u[8]; bf16x8 v; } vf;
#pragma unroll
          for (int e = 0; e < 8; ++e){
            const int rv = kc*32 + lg*8 + e;
            const int d = c2*16 + lq;
            vf.u[e] = vs[rv*32 + ((d >> 3) ^ ((rv >> 3) & 3))*8 + (d & 7)];
          }
          o[i][c2] = __builtin_amdgcn_mfma_f32_16x16x32_bf16(pa, vf.v, o[i][c2], 0, 0, 0);
        }
      }
      asm volatile("s_waitcnt lgkmcnt(0)" ::: "memory");   // pa/vf reads done
      __builtin_amdgcn_sched_barrier(0);
    }
    // write O head-slice into swizzled O tile
#pragma unroll
    for (int i = 0; i < 4; ++i){
#pragma unroll
      for (int c2 = 0; c2 < 2; ++c2){
#pragma unroll
        for (int r = 0; r < 4; ++r){
          const int row = i*16 + lg*4 + r;
          const int c = h*32 + c2*16 + lq;
          const int phys = (c >> 3) ^ (row & 7);
          O[row*512 + phys*8 + (c & 7)] = f2bf(o[i][c2][r]);
        }
      }
    }
  }
  __syncthreads();

  // ---- proj: C[64][512] = O @ W^T + bias ; wave -> cols [wid*64, +64) ----
  f32x4 pacc[4][4];
#pragma unroll
  for (int i = 0; i < 4; i++)
#pragma unroll
    for (int j = 0; j < 4; j++) pacc[i][j] = z;

  const int laneoff = (lq*4 + lg)*8;
#pragma unroll
  for (int ch = 0; ch < 16; ++ch){
    bf16x8 oa[4], wb[4];
#pragma unroll
    for (int nj = 0; nj < 4; ++nj){
      const int ct = wid*4 + nj;
      wb[nj] = *(const bf16x8*)(Wp + (ct*16 + ch)*512 + laneoff);
    }
#pragma unroll
    for (int mi = 0; mi < 4; ++mi){
      const int row = mi*16 + lq;
      const int phys = (ch*4 + lg) ^ (lq & 7);
      oa[mi] = *(const bf16x8*)&O[row*512 + phys*8];
    }
#pragma unroll
    for (int mi = 0; mi < 4; ++mi)
#pragma unroll
      for (int nj = 0; nj < 4; ++nj)
        pacc[mi][nj] = __builtin_amdgcn_mfma_f32_16x16x32_bf16(oa[mi], wb[nj], pacc[mi][nj], 0, 0, 0);
  }

  const int n0 = wid * 64;
  float bv[4];
#pragma unroll
  for (int nj = 0; nj < 4; ++nj) bv[nj] = projb[n0 + nj*16 + lq];
#pragma unroll
  for (int mi = 0; mi < 4; ++mi){
#pragma unroll
    for (int r = 0; r < 4; ++r){
      const size_t grow = (size_t)b*64 + mi*16 + lg*4 + r;
#pragma unroll
      for (int nj = 0; nj < 4; ++nj)
        out[grow*512 + n0 + nj*16 + lq] = pacc[mi][nj][r] + bv[nj];
    }
  }
}

extern "C" void kernel_launch(void* const* d_in, const int* in_sizes, int n_in,
                              void* d_out, int out_size, void* d_ws, size_t ws_size,
                              hipStream_t stream)
{
  const float* x      = (const float*)d_in[0];
  const float* qkvw   = (const float*)d_in[1];
  const float* qkvb   = (const float*)d_in[2];
  const float* projw  = (const float*)d_in[3];
  const float* projb  = (const float*)d_in[4];
  const float* table  = (const float*)d_in[5];
  const int*   relidx = (const int*)d_in[6];
  char* ws = (char*)d_ws;

  u16* qkvw_b = (u16*)(ws + 0);
  u16* Wp     = (u16*)(ws + 1572864);
  u16* biasT  = (u16*)(ws + 2097152);
  u16* scaleT = (u16*)(ws + 2228224);
  u16* qkvs   = (u16*)(ws + 2359296);      // [1024][16][3][64][32] bf16
  u16* xb     = (u16*)(ws + 203685888);    // x_bf16

  if (ws_size < 270794752ull) return;

  prep_kernel<<<dim3(4352), dim3(256), 0, stream>>>(qkvw, projw, table, relidx,
                                                    qkvw_b, Wp, biasT, scaleT);
  xconv_kernel<<<dim3(16384), dim3(256), 0, stream>>>(x, xb);
  gemm_qkv_kernel<<<dim3(1536), dim3(512), 0, stream>>>(xb, qkvw_b, qkvb, qkvs);
  attnproj_kernel<<<dim3(1024), dim3(512), 0, stream>>>(qkvs, biasT, scaleT,
                                                        Wp, projb, (float*)d_out);
}

// Round 11
// 284.105 us; speedup vs baseline: 1.0780x; 1.0780x over previous
//
#include <hip/hip_runtime.h>

typedef unsigned short u16;
typedef unsigned int   u32;
typedef __attribute__((ext_vector_type(8))) short bf16x8;
typedef __attribute__((ext_vector_type(4))) float f32x4;

#define SCALE 0.17677669529663687f  // 32^-0.5

__device__ __forceinline__ u16 f2bf(float f){
  u32 x = __float_as_uint(f);
  x += 0x7fffu + ((x >> 16) & 1u);   // RNE
  return (u16)(x >> 16);
}
__device__ __forceinline__ float bf2f(u16 u){
  return __uint_as_float(((u32)u) << 16);
}

// ---- ws layout (bytes) ----
// 0        : qkvw_bf16   [1536][512]            1,572,864
// 1572864  : projw_bf16  [512][512]               524,288
// 2097152  : biasT bf16  [16][64][16][4] permuted 131,072
// 2228224  : scaleT bf16 (same layout)            131,072
// 2359296  : qkv bf16 [65536][1536] coalesced   201,326,592
// 203685888: x_bf16 [65536][512] (reused attn_o) 67,108,864

// ---------------- prep: weights->bf16, permuted rel tables (r9-proven) ----------------
// bias/scale tables permuted: [h][row][lq][j] (j = col>>4, lq = col&15)
__global__ void prep_kernel(const float* __restrict__ qkvw, const float* __restrict__ projw,
                            const float* __restrict__ table, const int* __restrict__ relidx,
                            u16* __restrict__ qkvw_b, u16* __restrict__ projw_b,
                            u16* __restrict__ biasT, u16* __restrict__ scaleT){
  int i = blockIdx.x * 256 + threadIdx.x;
  if (i < 786432) {
    qkvw_b[i] = f2bf(qkvw[i]);
  } else if (i < 1048576) {
    int j = i - 786432; projw_b[j] = f2bf(projw[j]);
  } else if (i < 1114112) {
    int j = i - 1048576; int h = j >> 12, rc = j & 4095;
    int idx = relidx[rc];
    int row = rc >> 6, col = rc & 63;
    int noff = h*4096 + row*64 + (col & 15)*4 + (col >> 4);
    biasT [noff] = f2bf(table[idx*32 + h]);
    scaleT[noff] = f2bf(table[idx*32 + 16 + h]);
  }
}

// ---------------- x (fp32) -> bf16 ----------------
__global__ void xconv_kernel(const float* __restrict__ x, u16* __restrict__ xb){
  size_t i = (size_t)blockIdx.x * 256 + threadIdx.x;
  const float4* xp = (const float4*)x;
  float4 a = xp[2*i], b = xp[2*i+1];
  union { u16 u[8]; uint4 v; } o;
  o.u[0]=f2bf(a.x); o.u[1]=f2bf(a.y); o.u[2]=f2bf(a.z); o.u[3]=f2bf(a.w);
  o.u[4]=f2bf(b.x); o.u[5]=f2bf(b.y); o.u[6]=f2bf(b.z); o.u[7]=f2bf(b.w);
  *(uint4*)(xb + 8*i) = o.v;
}

// ============ GEMM (r4-verified, 128.4us): BM=BN=256, BK=32, 2-phase, ring-3 ============
// EPI 0: qkv epilogue (bias, q*=SCALE, bf16 to [M][1536])
// EPI 1: proj epilogue (bias, fp32 to [M][512])
template<int EPI>
__global__ __launch_bounds__(512, 2) void gemm_kernel(
    const u16* __restrict__ A, const u16* __restrict__ W,
    const float* __restrict__ bias, void* __restrict__ outp, const int NT)
{
  __shared__ u16 lds[3][16384];   // 3 x 32KB = 96KB
  const int tid = threadIdx.x, lane = tid & 63, wid = tid >> 6;
  const int wave_base = tid & ~63;

  const int cpx = gridDim.x >> 3;   // bijective XCD swizzle (grid % 8 == 0)
  const int bid = (blockIdx.x & 7) * cpx + (blockIdx.x >> 3);
  const int mt = bid / NT, nt = bid % NT;
  const size_t m0 = (size_t)mt * 256;
  const int n0 = nt * 256;
  const int wm = wid >> 2, wn = wid & 3;

  const f32x4 z = {0.f, 0.f, 0.f, 0.f};
  f32x4 acc[8][4];
#pragma unroll
  for (int i = 0; i < 8; i++)
#pragma unroll
    for (int j = 0; j < 4; j++) acc[i][j] = z;

  auto stageA = [&](int ch){
    const int slot = ch % 3;
    const int kb = ch * 32;
#pragma unroll
    for (int c = 0; c < 2; ++c){
      const int t = c*512 + tid;
      const int row = t >> 2, sl = t & 3;
      const int lsl = sl ^ ((row >> 1) & 3);
      const u16* ga = A + (m0 + row)*512 + kb + lsl*8;
      u16* la = &lds[slot][(size_t)(c*512 + wave_base)*8];
      __builtin_amdgcn_global_load_lds((const __attribute__((address_space(1))) u32*)ga,
                                       (__attribute__((address_space(3))) u32*)la, 16, 0, 0);
    }
  };
  auto stageB = [&](int ch){
    const int slot = ch % 3;
    const int kb = ch * 32;
#pragma unroll
    for (int c = 0; c < 2; ++c){
      const int t = c*512 + tid;
      const int col = t >> 2, sl = t & 3;
      const int lsl = sl ^ ((col >> 1) & 3);
      const u16* gb = W + (size_t)(n0 + col)*512 + kb + lsl*8;
      u16* lb = &lds[slot][8192 + (size_t)(c*512 + wave_base)*8];
      __builtin_amdgcn_global_load_lds((const __attribute__((address_space(1))) u32*)gb,
                                       (__attribute__((address_space(3))) u32*)lb, 16, 0, 0);
    }
  };

  stageA(0); stageB(0);
  stageA(1); stageB(1);
  asm volatile("s_waitcnt vmcnt(4)" ::: "memory");
  __builtin_amdgcn_s_barrier();

  const int lq = lane & 15, lk = lane >> 4;
#pragma unroll
  for (int ch = 0; ch < 16; ++ch){
    const int slot = ch % 3;
    const u16* As = &lds[slot][0];
    const u16* Bs = &lds[slot][8192];
    bf16x8 af[4], bfr[4], af2[4];

#pragma unroll
    for (int i = 0; i < 4; ++i){
      const int row = wm*128 + i*16 + lq;
      af[i]  = *(const bf16x8*)&As[row*32 + (lk ^ ((row >> 1) & 3))*8];
      const int col = wn*64 + i*16 + lq;
      bfr[i] = *(const bf16x8*)&Bs[col*32 + (lk ^ ((col >> 1) & 3))*8];
    }
    if (ch + 2 < 16) stageA(ch + 2);
    __builtin_amdgcn_s_barrier();
    asm volatile("s_waitcnt lgkmcnt(0)" ::: "memory");
    __builtin_amdgcn_sched_barrier(0);
    __builtin_amdgcn_s_setprio(1);
#pragma unroll
    for (int i = 0; i < 4; ++i)
#pragma unroll
      for (int j = 0; j < 4; ++j)
        acc[i][j] = __builtin_amdgcn_mfma_f32_16x16x32_bf16(af[i], bfr[j], acc[i][j], 0, 0, 0);
    __builtin_amdgcn_s_setprio(0);
    __builtin_amdgcn_s_barrier();

#pragma unroll
    for (int i = 0; i < 4; ++i){
      const int row = wm*128 + 64 + i*16 + lq;
      af2[i] = *(const bf16x8*)&As[row*32 + (lk ^ ((row >> 1) & 3))*8];
    }
    if (ch + 2 < 16) stageB(ch + 2);
    __builtin_amdgcn_s_barrier();
    asm volatile("s_waitcnt lgkmcnt(0)" ::: "memory");
    __builtin_amdgcn_sched_barrier(0);
    __builtin_amdgcn_s_setprio(1);
#pragma unroll
    for (int i = 0; i < 4; ++i)
#pragma unroll
      for (int j = 0; j < 4; ++j)
        acc[4+i][j] = __builtin_amdgcn_mfma_f32_16x16x32_bf16(af2[i], bfr[j], acc[4+i][j], 0, 0, 0);
    __builtin_amdgcn_s_setprio(0);
    if (ch < 14)       { asm volatile("s_waitcnt vmcnt(4)" ::: "memory"); }
    else if (ch == 14) { asm volatile("s_waitcnt vmcnt(0)" ::: "memory"); }
    if (ch < 15) __builtin_amdgcn_s_barrier();
  }

  const int lr = (lane >> 4) << 2;
  const int lc = lane & 15;
  if (EPI == 0){
    u16* o = (u16*)outp;
    float bv[4], sc[4];
#pragma unroll
    for (int nf = 0; nf < 4; ++nf){
      const int col = n0 + wn*64 + nf*16 + lc;
      bv[nf] = bias[col];
      sc[nf] = (col < 512) ? SCALE : 1.f;
    }
#pragma unroll
    for (int mf = 0; mf < 8; ++mf){
#pragma unroll
      for (int r = 0; r < 4; ++r){
        const size_t row = m0 + wm*128 + mf*16 + lr + r;
#pragma unroll
        for (int nf = 0; nf < 4; ++nf){
          const int col = n0 + wn*64 + nf*16 + lc;
          o[row*1536 + col] = f2bf((acc[mf][nf][r] + bv[nf]) * sc[nf]);
        }
      }
    }
  } else {
    float* o = (float*)outp;
    float bv[4];
#pragma unroll
    for (int nf = 0; nf < 4; ++nf)
      bv[nf] = bias[n0 + wn*64 + nf*16 + lc];
#pragma unroll
    for (int mf = 0; mf < 8; ++mf){
#pragma unroll
      for (int r = 0; r < 4; ++r){
        const size_t row = m0 + wm*128 + mf*16 + lr + r;
#pragma unroll
        for (int nf = 0; nf < 4; ++nf){
          const int col = n0 + wn*64 + nf*16 + lc;
          o[row*512 + col] = acc[mf][nf][r] + bv[nf];
        }
      }
    }
  }
}

// ---------------- attention: TWO heads per block, software-pipelined ----------------
// grid 8192 = 1024 windows x 8 head-pairs (consecutive blocks share a window ->
// L2 reuse). 256 thr / 4 waves; wave owns 16 q-rows (r4-proven body).
// Pipeline (T14): head1's q/k/v issued into REGS before head0 compute; LDS
// write after. Ps rows are wave-private -> lgkmcnt(0) instead of barrier.
__global__ __launch_bounds__(256) void attn_kernel(
    const u16* __restrict__ qkv, const u16* __restrict__ biasT,
    const u16* __restrict__ scaleT, u16* __restrict__ attn_out)
{
  __shared__ u16 qs[2][2560];   // [64][40]
  __shared__ u16 ks[2][2560];
  __shared__ u16 vs[2][2560];
  __shared__ u16 Ps[4608];      // [64][72], wave-private row bands
  const int tid = threadIdx.x, lane = tid & 63, wid = tid >> 6;
  const int lq = lane & 15, lg = lane >> 4;
  const int row = tid >> 2, sg = (tid & 3) * 8;
  const int b  = blockIdx.x >> 3;
  const int h0 = (blockIdx.x & 7) * 2;
  const u16* pbase = qkv + ((size_t)b*64 + row)*1536 + sg;
  const int wr0 = wid * 16;
  const f32x4 z = {0.f, 0.f, 0.f, 0.f};

  auto compute = [&](int buf, int h){
    bf16x8 qf = *(const bf16x8*)&qs[buf][(wr0 + lq)*40 + lg*8];
    f32x4 s[4];
#pragma unroll
    for (int ct = 0; ct < 4; ++ct){
      bf16x8 kf = *(const bf16x8*)&ks[buf][(ct*16 + lq)*40 + lg*8];
      s[ct] = __builtin_amdgcn_mfma_f32_16x16x32_bf16(qf, kf, z, 0, 0, 0);
    }
    const u16* bT = biasT + h*4096;
    const u16* sT = scaleT + h*4096;
#pragma unroll
    for (int r = 0; r < 4; ++r){
      const int rq = wr0 + lg*4 + r;
      const ushort4 b4 = *(const ushort4*)&bT[rq*64 + lq*4];
      const ushort4 s4 = *(const ushort4*)&sT[rq*64 + lq*4];
      float vals[4];
      vals[0] = s[0][r] + bf2f(b4.x);
      vals[1] = s[1][r] + bf2f(b4.y);
      vals[2] = s[2][r] + bf2f(b4.z);
      vals[3] = s[3][r] + bf2f(b4.w);
      float mx = fmaxf(fmaxf(vals[0], vals[1]), fmaxf(vals[2], vals[3]));
      mx = fmaxf(mx, __shfl_xor(mx, 1));
      mx = fmaxf(mx, __shfl_xor(mx, 2));
      mx = fmaxf(mx, __shfl_xor(mx, 4));
      mx = fmaxf(mx, __shfl_xor(mx, 8));
      float sm = 0.f;
#pragma unroll
      for (int j = 0; j < 4; ++j){ vals[j] = __expf(vals[j] - mx); sm += vals[j]; }
      sm += __shfl_xor(sm, 1);
      sm += __shfl_xor(sm, 2);
      sm += __shfl_xor(sm, 4);
      sm += __shfl_xor(sm, 8);
      const float inv = 1.f / sm;
      const u16 sv[4] = {s4.x, s4.y, s4.z, s4.w};
#pragma unroll
      for (int j = 0; j < 4; ++j)
        Ps[rq*72 + j*16 + lq] = f2bf(vals[j] * inv * bf2f(sv[j]));
    }
    asm volatile("s_waitcnt lgkmcnt(0)" ::: "memory");   // own Ps writes done
    __builtin_amdgcn_sched_barrier(0);

    f32x4 o[2] = {z, z};
#pragma unroll
    for (int kc = 0; kc < 2; ++kc){
      bf16x8 pa = *(const bf16x8*)&Ps[(wr0 + lq)*72 + kc*32 + lg*8];
#pragma unroll
      for (int c2 = 0; c2 < 2; ++c2){
        union { u16 u[8]; bf16x8 v; } vf;
#pragma unroll
        for (int e = 0; e < 8; ++e)
          vf.u[e] = vs[buf][(kc*32 + lg*8 + e)*40 + c2*16 + lq];
        o[c2] = __builtin_amdgcn_mfma_f32_16x16x32_bf16(pa, vf.v, o[c2], 0, 0, 0);
      }
    }
#pragma unroll
    for (int c2 = 0; c2 < 2; ++c2){
#pragma unroll
      for (int r = 0; r < 4; ++r){
        const int n = wr0 + lg*4 + r;
        attn_out[((size_t)b*64 + n)*512 + h*32 + c2*16 + lq] = f2bf(o[c2][r]);
      }
    }
  };

  // head 0: load + stage
  uint4 q0 = *(const uint4*)(pbase + h0*32);
  uint4 k0 = *(const uint4*)(pbase + 512 + h0*32);
  uint4 v0 = *(const uint4*)(pbase + 1024 + h0*32);
  *(uint4*)&qs[0][row*40 + sg] = q0;
  *(uint4*)&ks[0][row*40 + sg] = k0;
  *(uint4*)&vs[0][row*40 + sg] = v0;
  // head 1: issue loads early (latency hides under head-0 compute)
  uint4 q1 = *(const uint4*)(pbase + (h0+1)*32);
  uint4 k1 = *(const uint4*)(pbase + 512 + (h0+1)*32);
  uint4 v1 = *(const uint4*)(pbase + 1024 + (h0+1)*32);
  __syncthreads();

  compute(0, h0);

  *(uint4*)&qs[1][row*40 + sg] = q1;
  *(uint4*)&ks[1][row*40 + sg] = k1;
  *(uint4*)&vs[1][row*40 + sg] = v1;
  __syncthreads();

  compute(1, h0 + 1);
}

extern "C" void kernel_launch(void* const* d_in, const int* in_sizes, int n_in,
                              void* d_out, int out_size, void* d_ws, size_t ws_size,
                              hipStream_t stream)
{
  const float* x      = (const float*)d_in[0];
  const float* qkvw   = (const float*)d_in[1];
  const float* qkvb   = (const float*)d_in[2];
  const float* projw  = (const float*)d_in[3];
  const float* projb  = (const float*)d_in[4];
  const float* table  = (const float*)d_in[5];
  const int*   relidx = (const int*)d_in[6];
  char* ws = (char*)d_ws;

  u16* qkvw_b = (u16*)(ws + 0);
  u16* projw_b= (u16*)(ws + 1572864);
  u16* biasT  = (u16*)(ws + 2097152);
  u16* scaleT = (u16*)(ws + 2228224);
  u16* qkvws  = (u16*)(ws + 2359296);      // [65536][1536] bf16
  u16* xb     = (u16*)(ws + 203685888);    // x_bf16, reused as attn_o
  u16* attn_o = xb;

  if (ws_size < 270794752ull) return;

  prep_kernel<<<dim3(4352), dim3(256), 0, stream>>>(qkvw, projw, table, relidx,
                                                    qkvw_b, projw_b, biasT, scaleT);
  xconv_kernel<<<dim3(16384), dim3(256), 0, stream>>>(x, xb);
  gemm_kernel<0><<<dim3(1536), dim3(512), 0, stream>>>(xb, qkvw_b, qkvb, (void*)qkvws, 6);
  attn_kernel<<<dim3(8192), dim3(256), 0, stream>>>(qkvws, biasT, scaleT, attn_o);
  gemm_kernel<1><<<dim3(512), dim3(512), 0, stream>>>(attn_o, projw_b, projb, d_out, 2);
}